// Round 3
// baseline (228.222 us; speedup 1.0000x reference)
//
#include <hip/hip_runtime.h>

// DrQv2 random-shift augmentation.
// out[b,c,i,j] = x[b,c, clamp(i+sy-4,0,H-1), clamp(j+sx-4,0,W-1)]
//
// One block per (b,c) plane. Stage the 28 KB plane in LDS with aligned
// float4 streaming loads (fill-kernel access pattern), then do the
// shifted+clamped gather out of LDS and store aligned float4.

#define PAD 4

constexpr int NIMG   = 512;          // B*L
constexpr int C      = 9;
constexpr int H      = 84;
constexpr int W      = 84;
constexpr int PLANE  = H * W;        // 7056 floats (28224 B)
constexpr int PLANE4 = PLANE / 4;    // 1764 float4
constexpr int W4     = W / 4;        // 21 float4 per row

__device__ __forceinline__ void gather_one(const float* __restrict__ lds,
                                           float4* __restrict__ dst4,
                                           int p, int dx, int dy)
{
    int i  = p / W4;                  // output row
    int j4 = p - i * W4;              // float4 index within row
    int si = i + dy;
    si = si < 0 ? 0 : (si > H - 1 ? H - 1 : si);
    const float* __restrict__ row = lds + si * W;

    int j0 = (j4 << 2) + dx;
    int ja = j0;     ja = ja < 0 ? 0 : (ja > W - 1 ? W - 1 : ja);
    int jb = j0 + 1; jb = jb < 0 ? 0 : (jb > W - 1 ? W - 1 : jb);
    int jc = j0 + 2; jc = jc < 0 ? 0 : (jc > W - 1 ? W - 1 : jc);
    int jd = j0 + 3; jd = jd < 0 ? 0 : (jd > W - 1 ? W - 1 : jd);

    dst4[p] = make_float4(row[ja], row[jb], row[jc], row[jd]);
}

__global__ __launch_bounds__(256)
void drq_aug_kernel(const float* __restrict__ x,
                    const int*   __restrict__ shift,
                    float*       __restrict__ out)
{
    __shared__ float lds[PLANE];

    const int blk = blockIdx.x;            // blk = b*C + c
    const int b   = blk / C;
    const int dx  = shift[2 * b]     - PAD;   // block-uniform -> scalar
    const int dy  = shift[2 * b + 1] - PAD;

    const float4* __restrict__ src4 = (const float4*)(x   + (size_t)blk * PLANE);
    float4*       __restrict__ dst4 = (float4*)      (out + (size_t)blk * PLANE);
    float4*       __restrict__ lds4 = (float4*)lds;

    const int tid = threadIdx.x;

    // ---- stage: aligned streaming read of the whole plane ----
    #pragma unroll
    for (int r = 0; r < 6; ++r) {
        int p = r * 256 + tid;
        lds4[p] = src4[p];
    }
    {
        int p = 6 * 256 + tid;               // tail: 228 active
        if (p < PLANE4) lds4[p] = src4[p];
    }
    __syncthreads();

    // ---- gather from LDS, aligned streaming write ----
    #pragma unroll
    for (int r = 0; r < 6; ++r) {
        gather_one(lds, dst4, r * 256 + tid, dx, dy);
    }
    {
        int p = 6 * 256 + tid;
        if (p < PLANE4) gather_one(lds, dst4, p, dx, dy);
    }
}

extern "C" void kernel_launch(void* const* d_in, const int* in_sizes, int n_in,
                              void* d_out, int out_size, void* d_ws, size_t ws_size,
                              hipStream_t stream)
{
    const float* x     = (const float*)d_in[0];
    const int*   shift = (const int*)d_in[1];
    float*       out   = (float*)d_out;

    const int grid = NIMG * C;   // 4608 blocks, one per plane
    drq_aug_kernel<<<grid, 256, 0, stream>>>(x, shift, out);
}

// Round 4
// 225.763 us; speedup vs baseline: 1.0109x; 1.0109x over previous
//
#include <hip/hip_runtime.h>

// DrQv2 random-shift augmentation.
// out[b,c,i,j] = x[b,c, clamp(i+dy,0,H-1), clamp(j+dx,0,W-1)],  d = shift-PAD
//
// One block per (b,c) plane. Stage the 28 KB plane into LDS via
// __builtin_amdgcn_global_load_lds (async DMA, no VGPR round-trip, all 7
// 1KB-per-wave stages in flight), then shifted+clamped gather from LDS,
// aligned float4 store.

#define PAD 4

constexpr int NIMG   = 512;          // B*L
constexpr int C      = 9;
constexpr int H      = 84;
constexpr int W      = 84;
constexpr int PLANE  = H * W;        // 7056 floats (28224 B)
constexpr int PLANE4 = PLANE / 4;    // 1764 float4
constexpr int W4     = W / 4;        // 21 float4 per row
constexpr int LDSF4  = 7 * 256;      // 1792 float4 (28672 B) -- padded for tail

__device__ __forceinline__ void async_stage16(const float4* g, float4* l)
{
    __builtin_amdgcn_global_load_lds(
        (const __attribute__((address_space(1))) void*)g,
        (__attribute__((address_space(3))) void*)l,
        16, 0, 0);
}

__device__ __forceinline__ void gather_one(const float* __restrict__ lds,
                                           float4* __restrict__ dst4,
                                           int p, int dx, int dy)
{
    int i  = p / W4;                  // output row
    int j4 = p - i * W4;
    int si = i + dy;
    si = si < 0 ? 0 : (si > H - 1 ? H - 1 : si);
    const float* __restrict__ row = lds + si * W;

    int j0 = (j4 << 2) + dx;
    int ja = j0;     ja = ja < 0 ? 0 : (ja > W - 1 ? W - 1 : ja);
    int jb = j0 + 1; jb = jb < 0 ? 0 : (jb > W - 1 ? W - 1 : jb);
    int jc = j0 + 2; jc = jc < 0 ? 0 : (jc > W - 1 ? W - 1 : jc);
    int jd = j0 + 3; jd = jd < 0 ? 0 : (jd > W - 1 ? W - 1 : jd);

    dst4[p] = make_float4(row[ja], row[jb], row[jc], row[jd]);
}

__global__ __launch_bounds__(256)
void drq_aug_kernel(const float* __restrict__ x,
                    const int*   __restrict__ shift,
                    float*       __restrict__ out)
{
    __shared__ float4 lds4[LDSF4];
    const float* lds = (const float*)lds4;

    const int blk = blockIdx.x;            // blk = b*C + c
    const int b   = blk / C;
    const int dx  = shift[2 * b]     - PAD;   // block-uniform -> scalar
    const int dy  = shift[2 * b + 1] - PAD;

    const float4* __restrict__ src4 = (const float4*)(x   + (size_t)blk * PLANE);
    float4*       __restrict__ dst4 = (float4*)      (out + (size_t)blk * PLANE);

    const int tid  = threadIdx.x;
    const int wave = tid >> 6;

    // ---- stage: async global->LDS, 7 x (1 KB per wave), all in flight ----
    #pragma unroll
    for (int r = 0; r < 7; ++r) {
        int p  = r * 256 + tid;
        int ps = p < PLANE4 ? p : PLANE4 - 1;   // clamp source; dest is padded
        async_stage16(src4 + ps, lds4 + r * 256 + wave * 64);
    }
    __syncthreads();   // compiler emits s_waitcnt vmcnt(0) before s_barrier

    // ---- gather from LDS, aligned streaming float4 write ----
    #pragma unroll
    for (int r = 0; r < 6; ++r) {
        gather_one(lds, dst4, r * 256 + tid, dx, dy);
    }
    {
        int p = 6 * 256 + tid;                  // tail: 228 active
        if (p < PLANE4) gather_one(lds, dst4, p, dx, dy);
    }
}

extern "C" void kernel_launch(void* const* d_in, const int* in_sizes, int n_in,
                              void* d_out, int out_size, void* d_ws, size_t ws_size,
                              hipStream_t stream)
{
    const float* x     = (const float*)d_in[0];
    const int*   shift = (const int*)d_in[1];
    float*       out   = (float*)d_out;

    const int grid = NIMG * C;   // 4608 blocks, one per plane
    drq_aug_kernel<<<grid, 256, 0, stream>>>(x, shift, out);
}